// Round 7
// baseline (160.970 us; speedup 1.0000x reference)
//
#include <hip/hip_runtime.h>
#include <hip/hip_bf16.h>

// Problem constants
#define B_   256
#define L_   197
#define C_   768
#define H_   48
#define NA_  10
#define ROWS (B_ * L_)            // 50432
#define OFF_SIM 38731776          // B*L*C
#define OFF_IDX 38731777

typedef __attribute__((ext_vector_type(8))) short short8;
typedef __attribute__((ext_vector_type(4))) short short4_t;
typedef __attribute__((ext_vector_type(4))) float f32x4;

static __device__ inline short f2bf(float f) {
    union { float f; unsigned u; } v; v.f = f;
    unsigned r = v.u + 0x7fffu + ((v.u >> 16) & 1u);   // round-to-nearest-even
    return (short)(r >> 16);
}

// ---------------------------------------------------------------------------
// Kw: convert ALL 10 adapters' W1 [10,48,768] and W2 [10,768,48] to bf16.
// W2 stored K-padded to 64 (zeros) so GEMM2 can use 16x16x32 mfma.
// ---------------------------------------------------------------------------
__global__ void kw_convert(const float* __restrict__ W1, const float* __restrict__ W2,
                           short* __restrict__ W1b, short* __restrict__ W2b) {
    int i = blockIdx.x * 256 + threadIdx.x;
    if (i < NA_ * H_ * C_)                     // 368640
        W1b[i] = f2bf(W1[i]);
    if (i < NA_ * C_ * 64) {                   // 491520
        int k  = i & 63;
        int nc = i >> 6;                       // a*768 + c
        W2b[i] = (k < H_) ? f2bf(W2[nc * H_ + k]) : (short)0;
    }
}

// ---------------------------------------------------------------------------
// K1a: partial sums over L. grid = B*4 blocks of 192 threads; thread t owns
// float4-column t (cols 4t..4t+3). partial layout [b][seg][c] f32 (unchanged).
// ---------------------------------------------------------------------------
__global__ void k1a_partial(const float* __restrict__ x, float* __restrict__ partial) {
    int b = blockIdx.x >> 2, seg = blockIdx.x & 3;
    int l0 = seg * 50, l1 = l0 + 50; if (l1 > L_) l1 = L_;
    int t = threadIdx.x;                       // 0..191
    const float* xb = x + (size_t)b * L_ * C_ + t * 4;
    float4 s = {0.f, 0.f, 0.f, 0.f};
    #pragma unroll 5
    for (int l = l0; l < l1; ++l) {
        float4 v = *(const float4*)(xb + (size_t)l * C_);
        s.x += v.x; s.y += v.y; s.z += v.z; s.w += v.w;
    }
    *(float4*)(partial + ((size_t)b * 4 + seg) * C_ + t * 4) = s;
}

// ---------------------------------------------------------------------------
// K1b: per-b mean -> sims[b][k] (unchanged)
// ---------------------------------------------------------------------------
__global__ void k1b_sims(const float* __restrict__ partial, const float* __restrict__ akey,
                         float* __restrict__ sims) {
    __shared__ float red[21][256];
    int b = blockIdx.x, t = threadIdx.x;
    const float* p = partial + (size_t)b * 4 * C_;
    float m[3];
    #pragma unroll
    for (int j = 0; j < 3; ++j) {
        int c = t + j * 256;
        m[j] = (p[c] + p[C_ + c] + p[2 * C_ + c] + p[3 * C_ + c]) * (1.f / (float)L_);
    }
    red[0][t] = m[0] * m[0] + m[1] * m[1] + m[2] * m[2];
    #pragma unroll
    for (int k = 0; k < NA_; ++k) {
        float kd = 0.f, kq = 0.f;
        #pragma unroll
        for (int j = 0; j < 3; ++j) {
            float kv = akey[k * C_ + t + j * 256];
            kd += m[j] * kv; kq += kv * kv;
        }
        red[1 + k][t] = kd; red[11 + k][t] = kq;
    }
    __syncthreads();
    for (int s = 128; s > 0; s >>= 1) {
        if (t < s) {
            #pragma unroll
            for (int q = 0; q < 21; ++q) red[q][t] += red[q][t + s];
        }
        __syncthreads();
    }
    if (t < NA_) {
        float msq = red[0][0];
        sims[b * NA_ + t] = red[1 + t][0] * rsqrtf(fmaxf(red[11 + t][0], 1e-12f))
                                          * rsqrtf(fmaxf(msq, 1e-12f));
    }
}

// ---------------------------------------------------------------------------
// K2: single block. argmax + majority vote + reduce_sim + idx (unchanged)
// ---------------------------------------------------------------------------
__global__ void k2_select(const float* __restrict__ sims, float* __restrict__ out,
                          int* __restrict__ majorp) {
    __shared__ int counts[NA_];
    __shared__ int majorS;
    __shared__ float rs[256];
    int t = threadIdx.x;                       // = b
    float s[NA_];
    #pragma unroll
    for (int k = 0; k < NA_; ++k) s[k] = sims[t * NA_ + k];
    int best = 0; float bv = s[0];
    #pragma unroll
    for (int k = 1; k < NA_; ++k) { if (s[k] > bv) { bv = s[k]; best = k; } }
    if (t < NA_) counts[t] = 0;
    __syncthreads();
    atomicAdd(&counts[best], 1);
    __syncthreads();
    if (t == 0) {
        int mj = 0, mc = counts[0];
        #pragma unroll
        for (int k = 1; k < NA_; ++k) { if (counts[k] > mc) { mc = counts[k]; mj = k; } }
        majorS = mj; *majorp = mj;
    }
    __syncthreads();
    int mj = majorS;
    rs[t] = s[mj];
    __syncthreads();
    for (int st = 128; st > 0; st >>= 1) { if (t < st) rs[t] += rs[t + st]; __syncthreads(); }
    if (t == 0) out[OFF_SIM] = rs[0] * (1.f / (float)B_);
    out[OFF_IDX + t] = (float)mj;
}

// ---------------------------------------------------------------------------
// K3: fused adapter apply. grid = ROWS/32 blocks, 128 threads (2 waves).
// Phase 1: h = relu(x @ W1^T), 2-deep pipelined, h -> LDS (stride 72, K-pad 64).
// Phase 2: SWAPPED mfma (w2frag as A, hfrag as B) so D gives each lane 4
// consecutive columns of ONE row -> float4 x-read + float4 out-write.
// 2-deep software pipeline, fully unrolled (static buffer indices).
// ---------------------------------------------------------------------------
__launch_bounds__(128)
__global__ void k3_apply(const float* __restrict__ x, const short* __restrict__ W1b,
                         const short* __restrict__ W2b, const int* __restrict__ majorp,
                         float* __restrict__ out) {
    __shared__ short hb[32 * 72];
    const int major = *majorp;
    const short* w1 = W1b + major * (H_ * C_);
    const short* w2 = W2b + (size_t)major * (C_ * 64);

    int t = threadIdx.x;
    int w = t >> 6, l = t & 63;
    int rbase = blockIdx.x * 32 + w * 16;
    int lo16 = l & 15;
    int klane = (l >> 4) * 8;

    // zero the K-pad region [48,64) of this wave's 16 hb rows
    {
        int row = w * 16 + lo16;
        short4_t z = {0, 0, 0, 0};
        *(short4_t*)&hb[row * 72 + 48 + (l >> 4) * 4] = z;
    }

    // ---- phase 1: h[16][48] = relu(x_tile @ W1^T), prefetch depth 2 ----
    const float* xr  = x + (size_t)(rbase + lo16) * C_ + klane;
    const short* w1r = w1 + lo16 * C_ + klane;

    f32x4 acc0 = {0,0,0,0}, acc1 = {0,0,0,0}, acc2 = {0,0,0,0};
    float4 xa[3], xb[3];
    short8 wfa[3], wfb[3], wfc[3];
    #pragma unroll
    for (int s = 0; s < 2; ++s) {
        xa[s]  = *(const float4*)(xr + s * 32);
        xb[s]  = *(const float4*)(xr + s * 32 + 4);
        wfa[s] = *(const short8*)(w1r + s * 32);
        wfb[s] = *(const short8*)(w1r + 16 * C_ + s * 32);
        wfc[s] = *(const short8*)(w1r + 32 * C_ + s * 32);
    }
    #pragma unroll
    for (int i = 0; i < 24; ++i) {
        const int cur = i % 3;
        if (i + 2 < 24) {
            const int nxt = (i + 2) % 3;
            const int kk = (i + 2) * 32;
            xa[nxt]  = *(const float4*)(xr + kk);
            xb[nxt]  = *(const float4*)(xr + kk + 4);
            wfa[nxt] = *(const short8*)(w1r + kk);
            wfb[nxt] = *(const short8*)(w1r + 16 * C_ + kk);
            wfc[nxt] = *(const short8*)(w1r + 32 * C_ + kk);
        }
        short8 af;
        af[0] = f2bf(xa[cur].x); af[1] = f2bf(xa[cur].y);
        af[2] = f2bf(xa[cur].z); af[3] = f2bf(xa[cur].w);
        af[4] = f2bf(xb[cur].x); af[5] = f2bf(xb[cur].y);
        af[6] = f2bf(xb[cur].z); af[7] = f2bf(xb[cur].w);
        acc0 = __builtin_amdgcn_mfma_f32_16x16x32_bf16(af, wfa[cur], acc0, 0, 0, 0);
        acc1 = __builtin_amdgcn_mfma_f32_16x16x32_bf16(af, wfb[cur], acc1, 0, 0, 0);
        acc2 = __builtin_amdgcn_mfma_f32_16x16x32_bf16(af, wfc[cur], acc2, 0, 0, 0);
    }
    // store h tile to LDS (D layout: col = lane&15, row = (lane>>4)*4 + r)
    {
        int hrow0 = w * 16 + (l >> 4) * 4;
        #pragma unroll
        for (int r = 0; r < 4; ++r) {
            hb[(hrow0 + r) * 72 +  0 + lo16] = f2bf(fmaxf(acc0[r], 0.f));
            hb[(hrow0 + r) * 72 + 16 + lo16] = f2bf(fmaxf(acc1[r], 0.f));
            hb[(hrow0 + r) * 72 + 32 + lo16] = f2bf(fmaxf(acc2[r], 0.f));
        }
    }
    __syncthreads();

    // ---- phase 2: a = relu(h @ W2^T) via swapped-operand mfma ----
    // A = w2 frag (M = c-dim: row lo16 of tile, k = klane)
    // B = h frag  (N = x-row: lo16, k = klane)
    // D: lane holds rows m=(l>>4)*4+r (4 consecutive c), col n=lo16 (one x-row)
    short8 hA = *(const short8*)&hb[(w * 16 + lo16) * 72 + klane];
    short8 hB = *(const short8*)&hb[(w * 16 + lo16) * 72 + 32 + klane];
    const short* w2r = w2 + lo16 * 64 + klane;
    const float* xr2 = x   + (size_t)(rbase + lo16) * C_ + (l >> 4) * 4;
    float*      outr = out + (size_t)(rbase + lo16) * C_ + (l >> 4) * 4;

    short8 p0[3], p1[3];
    float4 xv[3];
    #pragma unroll
    for (int s = 0; s < 2; ++s) {
        p0[s] = *(const short8*)(w2r + s * 16 * 64);
        p1[s] = *(const short8*)(w2r + s * 16 * 64 + 32);
        xv[s] = *(const float4*)(xr2 + s * 16);
    }
    #pragma unroll
    for (int i = 0; i < 48; ++i) {
        const int cur = i % 3;
        if (i + 2 < 48) {
            const int nxt = (i + 2) % 3;
            p0[nxt] = *(const short8*)(w2r + (i + 2) * 16 * 64);
            p1[nxt] = *(const short8*)(w2r + (i + 2) * 16 * 64 + 32);
            xv[nxt] = *(const float4*)(xr2 + (i + 2) * 16);
        }
        f32x4 acc = {0,0,0,0};
        acc = __builtin_amdgcn_mfma_f32_16x16x32_bf16(p0[cur], hA, acc, 0, 0, 0);
        acc = __builtin_amdgcn_mfma_f32_16x16x32_bf16(p1[cur], hB, acc, 0, 0, 0);
        float4 ov;
        ov.x = xv[cur].x + fmaxf(acc[0], 0.f);
        ov.y = xv[cur].y + fmaxf(acc[1], 0.f);
        ov.z = xv[cur].z + fmaxf(acc[2], 0.f);
        ov.w = xv[cur].w + fmaxf(acc[3], 0.f);
        *(float4*)(outr + i * 16) = ov;
    }
}

// ---------------------------------------------------------------------------
extern "C" void kernel_launch(void* const* d_in, const int* in_sizes, int n_in,
                              void* d_out, int out_size, void* d_ws, size_t ws_size,
                              hipStream_t stream) {
    const float* x    = (const float*)d_in[0];
    const float* W1   = (const float*)d_in[1];
    const float* W2   = (const float*)d_in[2];
    const float* akey = (const float*)d_in[3];
    float* out = (float*)d_out;

    char* ws = (char*)d_ws;
    short* W1b     = (short*)ws;                       //   737,280 B
    short* W2b     = (short*)(ws + 737280);            //   983,040 B
    float* partial = (float*)(ws + 1720320);           // 3,145,728 B
    float* sims    = (float*)(ws + 4866048);           //    10,240 B
    int*   majorp  = (int*)(ws + 4876288);

    hipLaunchKernelGGL(kw_convert, dim3(1920), dim3(256), 0, stream, W1, W2, W1b, W2b);
    hipLaunchKernelGGL(k1a_partial, dim3(B_ * 4), dim3(192), 0, stream, x, partial);
    hipLaunchKernelGGL(k1b_sims, dim3(B_), dim3(256), 0, stream, partial, akey, sims);
    hipLaunchKernelGGL(k2_select, dim3(1), dim3(256), 0, stream, sims, out, majorp);
    hipLaunchKernelGGL(k3_apply, dim3(ROWS / 32), dim3(128), 0, stream, x, W1b, W2b, majorp, out);
}

// Round 9
// 152.145 us; speedup vs baseline: 1.0580x; 1.0580x over previous
//
#include <hip/hip_runtime.h>
#include <hip/hip_bf16.h>

// Problem constants
#define B_   256
#define L_   197
#define C_   768
#define H_   48
#define NA_  10
#define ROWS (B_ * L_)            // 50432
#define OFF_SIM 38731776          // B*L*C
#define OFF_IDX 38731777

typedef __attribute__((ext_vector_type(8))) short short8;
typedef __attribute__((ext_vector_type(4))) short short4_t;
typedef __attribute__((ext_vector_type(4))) float f32x4;

static __device__ inline short f2bf(float f) {
    union { float f; unsigned u; } v; v.f = f;
    unsigned r = v.u + 0x7fffu + ((v.u >> 16) & 1u);   // round-to-nearest-even
    return (short)(r >> 16);
}

// ---------------------------------------------------------------------------
// Kw: convert ALL 10 adapters' W1 [10,48,768] and W2 [10,768,48] to bf16.
// W2 stored K-padded to 64 (zeros) so GEMM2 can use 16x16x32 mfma.
// ---------------------------------------------------------------------------
__global__ void kw_convert(const float* __restrict__ W1, const float* __restrict__ W2,
                           short* __restrict__ W1b, short* __restrict__ W2b) {
    int i = blockIdx.x * 256 + threadIdx.x;
    if (i < NA_ * H_ * C_)                     // 368640
        W1b[i] = f2bf(W1[i]);
    if (i < NA_ * C_ * 64) {                   // 491520
        int k  = i & 63;
        int nc = i >> 6;                       // a*768 + c
        W2b[i] = (k < H_) ? f2bf(W2[nc * H_ + k]) : (short)0;
    }
}

// ---------------------------------------------------------------------------
// K1a: partial sums over L. grid = B*4 blocks of 192 threads; thread t owns
// float4-column t. partial layout [b][seg][c] f32.
// ---------------------------------------------------------------------------
__global__ void k1a_partial(const float* __restrict__ x, float* __restrict__ partial) {
    int b = blockIdx.x >> 2, seg = blockIdx.x & 3;
    int l0 = seg * 50, l1 = l0 + 50; if (l1 > L_) l1 = L_;
    int t = threadIdx.x;                       // 0..191
    const float* xb = x + (size_t)b * L_ * C_ + t * 4;
    float4 s = {0.f, 0.f, 0.f, 0.f};
    #pragma unroll 5
    for (int l = l0; l < l1; ++l) {
        float4 v = *(const float4*)(xb + (size_t)l * C_);
        s.x += v.x; s.y += v.y; s.z += v.z; s.w += v.w;
    }
    *(float4*)(partial + ((size_t)b * 4 + seg) * C_ + t * 4) = s;
}

// ---------------------------------------------------------------------------
// K1b: per-b mean -> sims[b][k] (unchanged)
// ---------------------------------------------------------------------------
__global__ void k1b_sims(const float* __restrict__ partial, const float* __restrict__ akey,
                         float* __restrict__ sims) {
    __shared__ float red[21][256];
    int b = blockIdx.x, t = threadIdx.x;
    const float* p = partial + (size_t)b * 4 * C_;
    float m[3];
    #pragma unroll
    for (int j = 0; j < 3; ++j) {
        int c = t + j * 256;
        m[j] = (p[c] + p[C_ + c] + p[2 * C_ + c] + p[3 * C_ + c]) * (1.f / (float)L_);
    }
    red[0][t] = m[0] * m[0] + m[1] * m[1] + m[2] * m[2];
    #pragma unroll
    for (int k = 0; k < NA_; ++k) {
        float kd = 0.f, kq = 0.f;
        #pragma unroll
        for (int j = 0; j < 3; ++j) {
            float kv = akey[k * C_ + t + j * 256];
            kd += m[j] * kv; kq += kv * kv;
        }
        red[1 + k][t] = kd; red[11 + k][t] = kq;
    }
    __syncthreads();
    for (int s = 128; s > 0; s >>= 1) {
        if (t < s) {
            #pragma unroll
            for (int q = 0; q < 21; ++q) red[q][t] += red[q][t + s];
        }
        __syncthreads();
    }
    if (t < NA_) {
        float msq = red[0][0];
        sims[b * NA_ + t] = red[1 + t][0] * rsqrtf(fmaxf(red[11 + t][0], 1e-12f))
                                          * rsqrtf(fmaxf(msq, 1e-12f));
    }
}

// ---------------------------------------------------------------------------
// K2: single block. argmax + majority vote + reduce_sim + idx (unchanged)
// ---------------------------------------------------------------------------
__global__ void k2_select(const float* __restrict__ sims, float* __restrict__ out,
                          int* __restrict__ majorp) {
    __shared__ int counts[NA_];
    __shared__ int majorS;
    __shared__ float rs[256];
    int t = threadIdx.x;                       // = b
    float s[NA_];
    #pragma unroll
    for (int k = 0; k < NA_; ++k) s[k] = sims[t * NA_ + k];
    int best = 0; float bv = s[0];
    #pragma unroll
    for (int k = 1; k < NA_; ++k) { if (s[k] > bv) { bv = s[k]; best = k; } }
    if (t < NA_) counts[t] = 0;
    __syncthreads();
    atomicAdd(&counts[best], 1);
    __syncthreads();
    if (t == 0) {
        int mj = 0, mc = counts[0];
        #pragma unroll
        for (int k = 1; k < NA_; ++k) { if (counts[k] > mc) { mc = counts[k]; mj = k; } }
        majorS = mj; *majorp = mj;
    }
    __syncthreads();
    int mj = majorS;
    rs[t] = s[mj];
    __syncthreads();
    for (int st = 128; st > 0; st >>= 1) { if (t < st) rs[t] += rs[t + st]; __syncthreads(); }
    if (t == 0) out[OFF_SIM] = rs[0] * (1.f / (float)B_);
    out[OFF_IDX + t] = (float)mj;
}

// ---------------------------------------------------------------------------
// K3: fused adapter apply. grid = ROWS/32 blocks, 128 threads (2 waves).
// Burst-structured for MLP: phase 1 = 6 bursts x 4 k-iters (all 20 loads of a
// burst issued as straight-line named values, then consumed). Phase 2 =
// 8 bursts x 6 c-iters (18 loads/burst), swapped-operand mfma, f32x4
// nontemporal out stores (keep x L3-resident).
// ---------------------------------------------------------------------------
__launch_bounds__(128)
__global__ void k3_apply(const float* __restrict__ x, const short* __restrict__ W1b,
                         const short* __restrict__ W2b, const int* __restrict__ majorp,
                         float* __restrict__ out) {
    __shared__ short hb[32 * 72];
    const int major = *majorp;
    const short* w1 = W1b + major * (H_ * C_);
    const short* w2 = W2b + (size_t)major * (C_ * 64);

    int t = threadIdx.x;
    int w = t >> 6, l = t & 63;
    int rbase = blockIdx.x * 32 + w * 16;
    int lo16 = l & 15;
    int klane = (l >> 4) * 8;

    // zero the K-pad region [48,64) of this wave's 16 hb rows
    {
        int row = w * 16 + lo16;
        short4_t z = {0, 0, 0, 0};
        *(short4_t*)&hb[row * 72 + 48 + (l >> 4) * 4] = z;
    }

    // ---- phase 1: h[16][48] = relu(x_tile @ W1^T), 6 bursts of 4 k-iters ----
    const float* xr  = x + (size_t)(rbase + lo16) * C_ + klane;
    const short* w1r = w1 + lo16 * C_ + klane;

    f32x4 acc0 = {0,0,0,0}, acc1 = {0,0,0,0}, acc2 = {0,0,0,0};

    #pragma unroll
    for (int j = 0; j < 6; ++j) {
        const int kb = j * 128;                // 4 iters x 32 floats
        // --- issue all 20 loads of this burst (x first: longest latency) ---
        float4 xa0 = *(const float4*)(xr + kb);
        float4 xb0 = *(const float4*)(xr + kb + 4);
        float4 xa1 = *(const float4*)(xr + kb + 32);
        float4 xb1 = *(const float4*)(xr + kb + 36);
        float4 xa2 = *(const float4*)(xr + kb + 64);
        float4 xb2 = *(const float4*)(xr + kb + 68);
        float4 xa3 = *(const float4*)(xr + kb + 96);
        float4 xb3 = *(const float4*)(xr + kb + 100);
        short8 wa0 = *(const short8*)(w1r + kb);
        short8 wb0 = *(const short8*)(w1r + 16 * C_ + kb);
        short8 wc0 = *(const short8*)(w1r + 32 * C_ + kb);
        short8 wa1 = *(const short8*)(w1r + kb + 32);
        short8 wb1 = *(const short8*)(w1r + 16 * C_ + kb + 32);
        short8 wc1 = *(const short8*)(w1r + 32 * C_ + kb + 32);
        short8 wa2 = *(const short8*)(w1r + kb + 64);
        short8 wb2 = *(const short8*)(w1r + 16 * C_ + kb + 64);
        short8 wc2 = *(const short8*)(w1r + 32 * C_ + kb + 64);
        short8 wa3 = *(const short8*)(w1r + kb + 96);
        short8 wb3 = *(const short8*)(w1r + 16 * C_ + kb + 96);
        short8 wc3 = *(const short8*)(w1r + 32 * C_ + kb + 96);
        // --- consume: 4 iterations ---
        short8 af;
        af[0] = f2bf(xa0.x); af[1] = f2bf(xa0.y); af[2] = f2bf(xa0.z); af[3] = f2bf(xa0.w);
        af[4] = f2bf(xb0.x); af[5] = f2bf(xb0.y); af[6] = f2bf(xb0.z); af[7] = f2bf(xb0.w);
        acc0 = __builtin_amdgcn_mfma_f32_16x16x32_bf16(af, wa0, acc0, 0, 0, 0);
        acc1 = __builtin_amdgcn_mfma_f32_16x16x32_bf16(af, wb0, acc1, 0, 0, 0);
        acc2 = __builtin_amdgcn_mfma_f32_16x16x32_bf16(af, wc0, acc2, 0, 0, 0);
        af[0] = f2bf(xa1.x); af[1] = f2bf(xa1.y); af[2] = f2bf(xa1.z); af[3] = f2bf(xa1.w);
        af[4] = f2bf(xb1.x); af[5] = f2bf(xb1.y); af[6] = f2bf(xb1.z); af[7] = f2bf(xb1.w);
        acc0 = __builtin_amdgcn_mfma_f32_16x16x32_bf16(af, wa1, acc0, 0, 0, 0);
        acc1 = __builtin_amdgcn_mfma_f32_16x16x32_bf16(af, wb1, acc1, 0, 0, 0);
        acc2 = __builtin_amdgcn_mfma_f32_16x16x32_bf16(af, wc1, acc2, 0, 0, 0);
        af[0] = f2bf(xa2.x); af[1] = f2bf(xa2.y); af[2] = f2bf(xa2.z); af[3] = f2bf(xa2.w);
        af[4] = f2bf(xb2.x); af[5] = f2bf(xb2.y); af[6] = f2bf(xb2.z); af[7] = f2bf(xb2.w);
        acc0 = __builtin_amdgcn_mfma_f32_16x16x32_bf16(af, wa2, acc0, 0, 0, 0);
        acc1 = __builtin_amdgcn_mfma_f32_16x16x32_bf16(af, wb2, acc1, 0, 0, 0);
        acc2 = __builtin_amdgcn_mfma_f32_16x16x32_bf16(af, wc2, acc2, 0, 0, 0);
        af[0] = f2bf(xa3.x); af[1] = f2bf(xa3.y); af[2] = f2bf(xa3.z); af[3] = f2bf(xa3.w);
        af[4] = f2bf(xb3.x); af[5] = f2bf(xb3.y); af[6] = f2bf(xb3.z); af[7] = f2bf(xb3.w);
        acc0 = __builtin_amdgcn_mfma_f32_16x16x32_bf16(af, wa3, acc0, 0, 0, 0);
        acc1 = __builtin_amdgcn_mfma_f32_16x16x32_bf16(af, wb3, acc1, 0, 0, 0);
        acc2 = __builtin_amdgcn_mfma_f32_16x16x32_bf16(af, wc3, acc2, 0, 0, 0);
    }

    // store h tile to LDS (D layout: col = lane&15, row = (lane>>4)*4 + r)
    {
        int hrow0 = w * 16 + (l >> 4) * 4;
        #pragma unroll
        for (int r = 0; r < 4; ++r) {
            hb[(hrow0 + r) * 72 +  0 + lo16] = f2bf(fmaxf(acc0[r], 0.f));
            hb[(hrow0 + r) * 72 + 16 + lo16] = f2bf(fmaxf(acc1[r], 0.f));
            hb[(hrow0 + r) * 72 + 32 + lo16] = f2bf(fmaxf(acc2[r], 0.f));
        }
    }
    __syncthreads();

    // ---- phase 2: a = relu(h @ W2^T), 8 bursts of 6 c-iters ----
    // A = w2 frag, B = h frag; D: lane holds 4 consecutive c of one x-row.
    short8 hA = *(const short8*)&hb[(w * 16 + lo16) * 72 + klane];
    short8 hB = *(const short8*)&hb[(w * 16 + lo16) * 72 + 32 + klane];
    const short* w2r = w2 + lo16 * 64 + klane;
    const float* xr2 = x   + (size_t)(rbase + lo16) * C_ + (l >> 4) * 4;
    float*      outr = out + (size_t)(rbase + lo16) * C_ + (l >> 4) * 4;

    #pragma unroll
    for (int j = 0; j < 8; ++j) {
        const int i0 = j * 6;
        // --- issue all 18 loads of this burst (x first) ---
        f32x4 xv0 = *(const f32x4*)(xr2 + (i0 + 0) * 16);
        f32x4 xv1 = *(const f32x4*)(xr2 + (i0 + 1) * 16);
        f32x4 xv2 = *(const f32x4*)(xr2 + (i0 + 2) * 16);
        f32x4 xv3 = *(const f32x4*)(xr2 + (i0 + 3) * 16);
        f32x4 xv4 = *(const f32x4*)(xr2 + (i0 + 4) * 16);
        f32x4 xv5 = *(const f32x4*)(xr2 + (i0 + 5) * 16);
        short8 p00 = *(const short8*)(w2r + (i0 + 0) * 1024);
        short8 p10 = *(const short8*)(w2r + (i0 + 0) * 1024 + 32);
        short8 p01 = *(const short8*)(w2r + (i0 + 1) * 1024);
        short8 p11 = *(const short8*)(w2r + (i0 + 1) * 1024 + 32);
        short8 p02 = *(const short8*)(w2r + (i0 + 2) * 1024);
        short8 p12 = *(const short8*)(w2r + (i0 + 2) * 1024 + 32);
        short8 p03 = *(const short8*)(w2r + (i0 + 3) * 1024);
        short8 p13 = *(const short8*)(w2r + (i0 + 3) * 1024 + 32);
        short8 p04 = *(const short8*)(w2r + (i0 + 4) * 1024);
        short8 p14 = *(const short8*)(w2r + (i0 + 4) * 1024 + 32);
        short8 p05 = *(const short8*)(w2r + (i0 + 5) * 1024);
        short8 p15 = *(const short8*)(w2r + (i0 + 5) * 1024 + 32);
        // --- consume: 6 iterations ---
        f32x4 acc;
        f32x4 ov;
        acc = (f32x4){0,0,0,0};
        acc = __builtin_amdgcn_mfma_f32_16x16x32_bf16(p00, hA, acc, 0, 0, 0);
        acc = __builtin_amdgcn_mfma_f32_16x16x32_bf16(p10, hB, acc, 0, 0, 0);
        ov[0] = xv0[0] + fmaxf(acc[0], 0.f); ov[1] = xv0[1] + fmaxf(acc[1], 0.f);
        ov[2] = xv0[2] + fmaxf(acc[2], 0.f); ov[3] = xv0[3] + fmaxf(acc[3], 0.f);
        __builtin_nontemporal_store(ov, (f32x4*)(outr + (i0 + 0) * 16));
        acc = (f32x4){0,0,0,0};
        acc = __builtin_amdgcn_mfma_f32_16x16x32_bf16(p01, hA, acc, 0, 0, 0);
        acc = __builtin_amdgcn_mfma_f32_16x16x32_bf16(p11, hB, acc, 0, 0, 0);
        ov[0] = xv1[0] + fmaxf(acc[0], 0.f); ov[1] = xv1[1] + fmaxf(acc[1], 0.f);
        ov[2] = xv1[2] + fmaxf(acc[2], 0.f); ov[3] = xv1[3] + fmaxf(acc[3], 0.f);
        __builtin_nontemporal_store(ov, (f32x4*)(outr + (i0 + 1) * 16));
        acc = (f32x4){0,0,0,0};
        acc = __builtin_amdgcn_mfma_f32_16x16x32_bf16(p02, hA, acc, 0, 0, 0);
        acc = __builtin_amdgcn_mfma_f32_16x16x32_bf16(p12, hB, acc, 0, 0, 0);
        ov[0] = xv2[0] + fmaxf(acc[0], 0.f); ov[1] = xv2[1] + fmaxf(acc[1], 0.f);
        ov[2] = xv2[2] + fmaxf(acc[2], 0.f); ov[3] = xv2[3] + fmaxf(acc[3], 0.f);
        __builtin_nontemporal_store(ov, (f32x4*)(outr + (i0 + 2) * 16));
        acc = (f32x4){0,0,0,0};
        acc = __builtin_amdgcn_mfma_f32_16x16x32_bf16(p03, hA, acc, 0, 0, 0);
        acc = __builtin_amdgcn_mfma_f32_16x16x32_bf16(p13, hB, acc, 0, 0, 0);
        ov[0] = xv3[0] + fmaxf(acc[0], 0.f); ov[1] = xv3[1] + fmaxf(acc[1], 0.f);
        ov[2] = xv3[2] + fmaxf(acc[2], 0.f); ov[3] = xv3[3] + fmaxf(acc[3], 0.f);
        __builtin_nontemporal_store(ov, (f32x4*)(outr + (i0 + 3) * 16));
        acc = (f32x4){0,0,0,0};
        acc = __builtin_amdgcn_mfma_f32_16x16x32_bf16(p04, hA, acc, 0, 0, 0);
        acc = __builtin_amdgcn_mfma_f32_16x16x32_bf16(p14, hB, acc, 0, 0, 0);
        ov[0] = xv4[0] + fmaxf(acc[0], 0.f); ov[1] = xv4[1] + fmaxf(acc[1], 0.f);
        ov[2] = xv4[2] + fmaxf(acc[2], 0.f); ov[3] = xv4[3] + fmaxf(acc[3], 0.f);
        __builtin_nontemporal_store(ov, (f32x4*)(outr + (i0 + 4) * 16));
        acc = (f32x4){0,0,0,0};
        acc = __builtin_amdgcn_mfma_f32_16x16x32_bf16(p05, hA, acc, 0, 0, 0);
        acc = __builtin_amdgcn_mfma_f32_16x16x32_bf16(p15, hB, acc, 0, 0, 0);
        ov[0] = xv5[0] + fmaxf(acc[0], 0.f); ov[1] = xv5[1] + fmaxf(acc[1], 0.f);
        ov[2] = xv5[2] + fmaxf(acc[2], 0.f); ov[3] = xv5[3] + fmaxf(acc[3], 0.f);
        __builtin_nontemporal_store(ov, (f32x4*)(outr + (i0 + 5) * 16));
    }
}

// ---------------------------------------------------------------------------
extern "C" void kernel_launch(void* const* d_in, const int* in_sizes, int n_in,
                              void* d_out, int out_size, void* d_ws, size_t ws_size,
                              hipStream_t stream) {
    const float* x    = (const float*)d_in[0];
    const float* W1   = (const float*)d_in[1];
    const float* W2   = (const float*)d_in[2];
    const float* akey = (const float*)d_in[3];
    float* out = (float*)d_out;

    char* ws = (char*)d_ws;
    short* W1b     = (short*)ws;                       //   737,280 B
    short* W2b     = (short*)(ws + 737280);            //   983,040 B
    float* partial = (float*)(ws + 1720320);           // 3,145,728 B
    float* sims    = (float*)(ws + 4866048);           //    10,240 B
    int*   majorp  = (int*)(ws + 4876288);

    hipLaunchKernelGGL(kw_convert, dim3(1920), dim3(256), 0, stream, W1, W2, W1b, W2b);
    hipLaunchKernelGGL(k1a_partial, dim3(B_ * 4), dim3(192), 0, stream, x, partial);
    hipLaunchKernelGGL(k1b_sims, dim3(B_), dim3(256), 0, stream, partial, akey, sims);
    hipLaunchKernelGGL(k2_select, dim3(1), dim3(256), 0, stream, sims, out, majorp);
    hipLaunchKernelGGL(k3_apply, dim3(ROWS / 32), dim3(128), 0, stream, x, W1b, W2b, majorp, out);
}